// Round 16
// baseline (194.687 us; speedup 1.0000x reference)
//
#include <hip/hip_runtime.h>
#include <hip/hip_bf16.h>

#define DEVI __device__ __forceinline__

typedef __attribute__((ext_vector_type(8))) __bf16 bf16x8;
typedef __attribute__((ext_vector_type(4))) float f32x4;
typedef __attribute__((ext_vector_type(16))) float f32x16;
typedef __attribute__((ext_vector_type(8))) unsigned short ushort8;
typedef __attribute__((ext_vector_type(4))) int i32x4;

constexpr int D_MODEL = 1024;
constexpr int NHEAD   = 16;
constexpr int SEQ     = 2048;
constexpr int BATCH   = 4;
constexpr int MTOK    = BATCH * SEQ;   // 8192

DEVI unsigned short f2bf(float x) {
  __hip_bfloat16 h = __float2bfloat16(x);
  return __builtin_bit_cast(unsigned short, h);
}

DEVI bf16x8 ld_bf8(const unsigned short* p) {
  ushort8 u = *reinterpret_cast<const ushort8*>(p);
  return __builtin_bit_cast(bf16x8, u);
}

DEVI void gload_lds16(const void* g, void* l) {
  __builtin_amdgcn_global_load_lds(
      (const __attribute__((address_space(1))) void*)g,
      (__attribute__((address_space(3))) void*)l, 16, 0, 0);
}

// pack 2 f32 -> u32 of 2 bf16 (RNE)
DEVI int cvtpk(float a, float b) {
  int r;
  asm("v_cvt_pk_bf16_f32 %0, %1, %2" : "=v"(r) : "v"(a), "v"(b));
  return r;
}
// swap a[lanes 32:63] <-> b[lanes 0:31]  (operands MUST hold distinct values --
// equal-valued operands may land in one VGPR, making the swap a no-op; that
// aliasing broke R3's cross-half reduce)
DEVI void pswap(int& a, int& b) {
  asm volatile("v_permlane32_swap_b32 %0, %1" : "+v"(a), "+v"(b));
}
// cross-half combine via shfl (safe codegen)
DEVI float xhalf_sum(float x) { return x + __shfl_xor(x, 32, 64); }

DEVI float tree16sum(const float* p) {
  float a = p[0] + p[1], b = p[2] + p[3], c = p[4] + p[5], d = p[6] + p[7];
  float e = p[8] + p[9], f = p[10] + p[11], g = p[12] + p[13], h = p[14] + p[15];
  a += b; c += d; e += f; g += h;
  return (a + c) + (e + g);
}
// build A/B-fragment (k = hi*8 + i) from 8 P values (keys off..off+7 in C-row order)
DEVI bf16x8 mk_frag(const float* p, int off) {
  int w0 = cvtpk(p[off + 0], p[off + 1]);
  int w1 = cvtpk(p[off + 2], p[off + 3]);
  int w2 = cvtpk(p[off + 4], p[off + 5]);
  int w3 = cvtpk(p[off + 6], p[off + 7]);
  pswap(w0, w2);
  pswap(w1, w3);
  i32x4 v{w0, w1, w2, w3};
  return __builtin_bit_cast(bf16x8, v);
}

// ---------------- fused prep: weight transpose (z<4) + x fp32->bf16 (z>=4) ----
__global__ void prep_kernel(const float* __restrict__ x, unsigned short* __restrict__ xb,
                            const float* __restrict__ Wq, const float* __restrict__ Wk,
                            const float* __restrict__ Wv, const float* __restrict__ Wo,
                            unsigned short* __restrict__ Wtq, unsigned short* __restrict__ Wtk,
                            unsigned short* __restrict__ Wtv, unsigned short* __restrict__ Wto) {
  const int z = blockIdx.z;
  if (z >= 4) {
    // x conversion: 512 blocks x 256 thr x 16 float4 = 8.39M floats
    const int bid = (z - 4) * 256 + blockIdx.y * 16 + blockIdx.x;
    const float4* in4 = reinterpret_cast<const float4*>(x);
    ushort4* out4 = reinterpret_cast<ushort4*>(xb);
#pragma unroll
    for (int j = 0; j < 16; ++j) {
      const int i4 = bid * 4096 + j * 256 + threadIdx.x;
      float4 v = in4[i4];
      ushort4 o;
      o.x = f2bf(v.x); o.y = f2bf(v.y); o.z = f2bf(v.z); o.w = f2bf(v.w);
      out4[i4] = o;
    }
    return;
  }
  __shared__ float tile[64][65];
  const float* W = z == 0 ? Wq : z == 1 ? Wk : z == 2 ? Wv : Wo;
  unsigned short* Wt = z == 0 ? Wtq : z == 1 ? Wtk : z == 2 ? Wtv : Wto;
  const int k0 = blockIdx.x * 64, n0 = blockIdx.y * 64;
  const int tx = threadIdx.x & 63, ty = threadIdx.x >> 6;
  for (int r = ty; r < 64; r += 4)
    tile[r][tx] = W[(size_t)(k0 + r) * D_MODEL + n0 + tx];
  __syncthreads();
  for (int r = ty; r < 64; r += 4)
    Wt[(size_t)(n0 + r) * D_MODEL + k0 + tx] = f2bf(tile[tx][r]);
}

// ---------------- GEMM: C[M=8192][N=1024] = A(bf16) * Wt^T + bias ----------------
// Counted-vmcnt pipeline (T4, proven R11): stage(kt+1) issues 8 vmem/wave;
// s_waitcnt vmcnt(8) waits only the PREVIOUS tile's 8 loads. Raw s_barrier;
// sched_barrier(0) fences per rule 18. Separate launches per R8/R12 lesson:
// QKV fusion is slower regardless of L2 mapping.
__global__ __launch_bounds__(256) void gemm128(
    const unsigned short* __restrict__ A,
    const unsigned short* __restrict__ Bt,
    const float* __restrict__ bias,
    void* __restrict__ outp, int mode, float scale) {
  constexpr int K = 1024, N = 1024, KT = K / 64;
  __shared__ __align__(16) unsigned short As[2][128 * 64];
  __shared__ __align__(16) unsigned short Bs[2][128 * 64];
  const int t = threadIdx.x;
  const int w = t >> 6, l = t & 63;
  // XCD swizzle (bijective: 512 % 8 == 0): A-chunk 2MB + B 2MB = one 4MB L2.
  const int bid2 = ((blockIdx.x & 7) << 6) | (blockIdx.x >> 3);
  const int bm = bid2 >> 3, bn = bid2 & 7;
  const int m0 = bm * 128, n0 = bn * 128;
  const int wm = (w >> 1) * 64, wn = (w & 1) * 64;
  const int lr = l & 15, lg = l >> 4;

  f32x4 acc[4][4] = {};

  auto stage = [&](int kt, int buf) {
    const int k0 = kt * 64;
#pragma unroll
    for (int p = 0; p < 4; ++p) {
      const int seg = p * 4 + w;
      const int row = seg * 8 + (l >> 3);
      const int c = (l & 7) ^ (row & 7);
      gload_lds16(A + (size_t)(m0 + row) * K + k0 + c * 8, &As[buf][seg * 512]);
      gload_lds16(Bt + (size_t)(n0 + row) * K + k0 + c * 8, &Bs[buf][seg * 512]);
    }
  };

  stage(0, 0);
  __syncthreads();   // prologue: full drain once

  for (int kt = 0; kt < KT; ++kt) {
    const int cur = kt & 1;
    if (kt + 1 < KT) {
      stage(kt + 1, cur ^ 1);   // 8 vmem instrs issued per wave
      asm volatile("s_waitcnt vmcnt(8)" ::: "memory");  // prev tile's 8 done
    } else {
      asm volatile("s_waitcnt vmcnt(0)" ::: "memory");  // last tile: drain
    }
    __builtin_amdgcn_sched_barrier(0);
    __builtin_amdgcn_s_barrier();   // all waves see buf[cur] complete
#pragma unroll
    for (int ks = 0; ks < 2; ++ks) {
      bf16x8 af[4], bfr[4];
      const int kk = lg + ks * 4;
#pragma unroll
      for (int i = 0; i < 4; ++i) {
        const int rowA = wm + i * 16 + lr;
        af[i] = ld_bf8(&As[cur][rowA * 64 + ((kk ^ (rowA & 7)) * 8)]);
        const int rowB = wn + i * 16 + lr;
        bfr[i] = ld_bf8(&Bs[cur][rowB * 64 + ((kk ^ (rowB & 7)) * 8)]);
      }
#pragma unroll
      for (int mi = 0; mi < 4; ++mi)
#pragma unroll
        for (int ni = 0; ni < 4; ++ni)
          acc[mi][ni] = __builtin_amdgcn_mfma_f32_16x16x32_bf16(
              af[mi], bfr[ni], acc[mi][ni], 0, 0, 0);
    }
    __builtin_amdgcn_sched_barrier(0);
    __builtin_amdgcn_s_barrier();   // buf[cur] reads done before next stage overwrites
  }

#pragma unroll
  for (int ni = 0; ni < 4; ++ni) {
    const int n = n0 + wn + ni * 16 + lr;
    const float bv = bias[n];
#pragma unroll
    for (int mi = 0; mi < 4; ++mi) {
#pragma unroll
      for (int r = 0; r < 4; ++r) {
        const int m = m0 + wm + mi * 16 + lg * 4 + r;
        const float v = (acc[mi][ni][r] + bv) * scale;
        if (mode == 2) {
          ((float*)outp)[(size_t)m * N + n] = v;
        } else {
          const int b = m >> 11, s = m & 2047, h = n >> 6, dk = n & 63;
          unsigned short* o = (unsigned short*)outp;
          if (mode == 0)
            o[(((size_t)(b * NHEAD + h) * SEQ + s) << 6) + dk] = f2bf(v);
          else
            o[(((size_t)(b * NHEAD + h) << 6) + dk) * SEQ + s] = f2bf(v);
        }
      }
    }
  }
}

// ---------------- causal flash attention v9: equal-length q-tile pairing ----
// Q: [B*H][S][64] bf16 (pre-scaled by 0.125*log2e); Kt: [B*H][S][64];
// Vt: [B*H][64][S]; Oa: [B][S][1024] bf16.
// Each block processes TWO q-tiles sequentially: qt = 15-p then qt = p
// (p = bid>>6). Every block = exactly 34 tile-units -> zero makespan tail
// (R13's 4-blocks/CU decayed 16->4 waves; here 8 waves/CU constant).
// Per segment: fresh Q-frags, psum/oacc reset, full R13 tile loop (counted
// vmcnt), epilogue. Segment boundary safe: trailing s_barrier orders all LDS
// reads before next segment's stage; last tile drained vmcnt(0).
__global__ __launch_bounds__(256) void attn_kernel(
    const unsigned short* __restrict__ Q,
    const unsigned short* __restrict__ Kt,
    const unsigned short* __restrict__ Vt,
    unsigned short* __restrict__ Oa) {
  __shared__ __align__(16) unsigned short Ks[2][64 * 64];
  __shared__ __align__(16) unsigned short Vs[2][64 * 64];
  const int t = threadIdx.x, w = t >> 6, l = t & 63;
  const int ph = blockIdx.x >> 6;     // pair id 0..7
  const int bh = blockIdx.x & 63;
  const int l31 = l & 31, hi = l >> 5;
  const int b = bh >> 4, h = bh & 15;

  auto stage = [&](int jtile, int buf) {
#pragma unroll
    for (int i = 0; i < 2; ++i) {
      const int seg = w * 2 + i;
      const int row = seg * 8 + (l >> 3);
      const int cg = (l & 7) ^ (row & 7);   // pre-swizzled source chunk
      gload_lds16(Kt + (((size_t)bh * SEQ + jtile * 64 + row) << 6) + cg * 8,
                  &Ks[buf][seg * 512]);
      gload_lds16(Vt + ((size_t)bh * 64 + row) * SEQ + jtile * 64 + cg * 8,
                  &Vs[buf][seg * 512]);
    }
  };

#pragma unroll 1
  for (int sg = 0; sg < 2; ++sg) {
    const int qt = sg == 0 ? 15 - ph : ph;   // heavy segment first
    const int jcnt = 2 * qt + 2;
    const int q0w = qt * 128 + w * 32;
    const int qg = q0w + l31;           // this lane's q row

    // Q B-fragments: col=q=l31, k = ks*16 + hi*8 + i  (reused all tiles)
    const unsigned short* Qb = Q + ((size_t)bh * SEQ + qg) * 64;
    bf16x8 qf[4];
#pragma unroll
    for (int ks = 0; ks < 4; ++ks)
      qf[ks] = ld_bf8(Qb + ks * 16 + hi * 8);

    f32x16 psum = {};     // deferred softmax denominator (per C-slot)
    f32x16 oacc[2] = {};  // O^T: col=q=l31, row=d = dt*32+(r&3)+8*(r>>2)+4*hi

    stage(0, 0);
    __syncthreads();   // segment prologue: full drain

    for (int jt = 0; jt < jcnt; ++jt) {
      const int cur = jt & 1;
      if (jt + 1 < jcnt) {
        stage(jt + 1, cur ^ 1);   // 4 vmem instrs issued per wave
        asm volatile("s_waitcnt vmcnt(4)" ::: "memory");  // prev tile's 4 done
      } else {
        asm volatile("s_waitcnt vmcnt(0)" ::: "memory");  // last tile: drain
      }
      __builtin_amdgcn_sched_barrier(0);
      __builtin_amdgcn_s_barrier();   // buf[cur] complete across all waves
      const int j0 = jt * 64;
      const bool active = (j0 <= q0w + 31);   // wave-uniform
      if (active) {
        const bool live1 = (j0 < q0w);        // key subtile 1 has unmasked keys
        const bool maskT = (j0 + 32 >= q0w);  // tile needs causal masking

        // S^T = K * Q^T   (A=K rows=key, B=Q cols=q)
        f32x16 s0 = {}, s1 = {};
        __builtin_amdgcn_s_setprio(1);
#pragma unroll
        for (int ks = 0; ks < 4; ++ks) {
          bf16x8 kf = ld_bf8(&Ks[cur][l31 * 64 + ((((ks << 1) | hi) ^ (l31 & 7)) << 3)]);
          s0 = __builtin_amdgcn_mfma_f32_32x32x16_bf16(kf, qf[ks], s0, 0, 0, 0);
        }
        if (live1) {
#pragma unroll
          for (int ks = 0; ks < 4; ++ks) {
            const int r1 = 32 + l31;
            bf16x8 kf = ld_bf8(&Ks[cur][r1 * 64 + ((((ks << 1) | hi) ^ (r1 & 7)) << 3)]);
            s1 = __builtin_amdgcn_mfma_f32_32x32x16_bf16(kf, qf[ks], s1, 0, 0, 0);
          }
        }
        __builtin_amdgcn_s_setprio(0);

        // P = exp2(S) (masked -> 0), accumulate denominator
        float p0[16];
        if (maskT) {
#pragma unroll
          for (int r = 0; r < 16; ++r) {
            const int key = j0 + (r & 3) + ((r >> 2) << 3) + (hi << 2);
            p0[r] = (key > qg) ? 0.f : exp2f(s0[r]);
          }
        } else {
#pragma unroll
          for (int r = 0; r < 16; ++r) p0[r] = exp2f(s0[r]);
        }
#pragma unroll
        for (int r = 0; r < 16; ++r) psum[r] += p0[r];

        // O^T += V^T * P^T  (A=V^T rows=d from Vs, B=P^T cols=q from regs)
        __builtin_amdgcn_s_setprio(1);
#pragma unroll
        for (int ks = 0; ks < 2; ++ks) {
          bf16x8 pf = mk_frag(p0, ks * 8);
#pragma unroll
          for (int dt = 0; dt < 2; ++dt) {
            const int rv = dt * 32 + l31;
            bf16x8 vf = ld_bf8(&Vs[cur][rv * 64 + ((((ks << 1) | hi) ^ (rv & 7)) << 3)]);
            oacc[dt] = __builtin_amdgcn_mfma_f32_32x32x16_bf16(vf, pf, oacc[dt], 0, 0, 0);
          }
        }
        __builtin_amdgcn_s_setprio(0);

        if (live1) {
          float p1[16];
          if (maskT) {
#pragma unroll
            for (int r = 0; r < 16; ++r) {
              const int key = j0 + 32 + (r & 3) + ((r >> 2) << 3) + (hi << 2);
              p1[r] = (key > qg) ? 0.f : exp2f(s1[r]);
            }
          } else {
#pragma unroll
            for (int r = 0; r < 16; ++r) p1[r] = exp2f(s1[r]);
          }
#pragma unroll
          for (int r = 0; r < 16; ++r) psum[r] += p1[r];
          __builtin_amdgcn_s_setprio(1);
#pragma unroll
          for (int ks = 0; ks < 2; ++ks) {
            bf16x8 pf = mk_frag(p1, ks * 8);
#pragma unroll
            for (int dt = 0; dt < 2; ++dt) {
              const int rv = dt * 32 + l31;
              bf16x8 vf = ld_bf8(&Vs[cur][rv * 64 + (((((ks + 2) << 1) | hi) ^ (rv & 7)) << 3)]);
              oacc[dt] = __builtin_amdgcn_mfma_f32_32x32x16_bf16(vf, pf, oacc[dt], 0, 0, 0);
            }
          }
          __builtin_amdgcn_s_setprio(0);
        }
      }
      __builtin_amdgcn_sched_barrier(0);
      __builtin_amdgcn_s_barrier();   // buf[cur] reads done before next stage overwrites
    }

    // segment epilogue: reduce denominator once; lane writes its q row
    float pa[16];
#pragma unroll
    for (int r = 0; r < 16; ++r) pa[r] = psum[r];
    const float l_ = xhalf_sum(tree16sum(pa));
    const float rinv = 1.f / l_;
    unsigned short* orow = Oa + ((size_t)(b * SEQ) + qg) * D_MODEL + h * 64;
#pragma unroll
    for (int dt = 0; dt < 2; ++dt)
#pragma unroll
      for (int g = 0; g < 4; ++g) {
        const int d = dt * 32 + g * 8 + hi * 4;
        uint2 u;
        u.x = (unsigned)cvtpk(oacc[dt][g * 4 + 0] * rinv, oacc[dt][g * 4 + 1] * rinv);
        u.y = (unsigned)cvtpk(oacc[dt][g * 4 + 2] * rinv, oacc[dt][g * 4 + 3] * rinv);
        *reinterpret_cast<uint2*>(orow + d) = u;
      }
  }
}

// ---------------- launch ----------------
extern "C" void kernel_launch(void* const* d_in, const int* in_sizes, int n_in,
                              void* d_out, int out_size, void* d_ws, size_t ws_size,
                              hipStream_t stream) {
  const float* x  = (const float*)d_in[0];
  const float* Wq = (const float*)d_in[1];
  const float* bq = (const float*)d_in[2];
  const float* Wk = (const float*)d_in[3];
  const float* bk = (const float*)d_in[4];
  const float* Wv = (const float*)d_in[5];
  const float* bv = (const float*)d_in[6];
  const float* Wo = (const float*)d_in[7];
  const float* bo = (const float*)d_in[8];

  char* ws = (char*)d_ws;
  unsigned short* xb    = (unsigned short*)(ws + 0);
  unsigned short* attnb = (unsigned short*)(ws + 0);  // alias: x dead after V GEMM
  unsigned short* wtq   = (unsigned short*)(ws + 16777216);
  unsigned short* wtk   = (unsigned short*)(ws + 18874368);
  unsigned short* wtv   = (unsigned short*)(ws + 20971520);
  unsigned short* wto   = (unsigned short*)(ws + 23068672);
  unsigned short* Qw    = (unsigned short*)(ws + 25165824);
  unsigned short* Kw    = (unsigned short*)(ws + 41943040);
  unsigned short* Vtw   = (unsigned short*)(ws + 58720256);

  prep_kernel<<<dim3(16, 16, 6), 256, 0, stream>>>(x, xb, Wq, Wk, Wv, Wo,
                                                   wtq, wtk, wtv, wto);

  // Q pre-scaled by 1/sqrt(Dk) * log2(e): attention softmax runs in exp2 domain
  gemm128<<<512, 256, 0, stream>>>(xb, wtq, bq, (void*)Qw, 0, 0.18033688011112042f);
  gemm128<<<512, 256, 0, stream>>>(xb, wtk, bk, (void*)Kw, 0, 1.0f);
  gemm128<<<512, 256, 0, stream>>>(xb, wtv, bv, (void*)Vtw, 1, 1.0f);

  attn_kernel<<<512, 256, 0, stream>>>(Qw, Kw, Vtw, attnb);

  gemm128<<<512, 256, 0, stream>>>(attnb, wto, bo, d_out, 2, 1.0f);
}

// Round 17
// 192.027 us; speedup vs baseline: 1.0138x; 1.0138x over previous
//
#include <hip/hip_runtime.h>
#include <hip/hip_bf16.h>

#define DEVI __device__ __forceinline__

typedef __attribute__((ext_vector_type(8))) __bf16 bf16x8;
typedef __attribute__((ext_vector_type(4))) float f32x4;
typedef __attribute__((ext_vector_type(16))) float f32x16;
typedef __attribute__((ext_vector_type(8))) unsigned short ushort8;
typedef __attribute__((ext_vector_type(4))) int i32x4;

constexpr int D_MODEL = 1024;
constexpr int NHEAD   = 16;
constexpr int SEQ     = 2048;
constexpr int BATCH   = 4;
constexpr int MTOK    = BATCH * SEQ;   // 8192

DEVI unsigned short f2bf(float x) {
  __hip_bfloat16 h = __float2bfloat16(x);
  return __builtin_bit_cast(unsigned short, h);
}

DEVI bf16x8 ld_bf8(const unsigned short* p) {
  ushort8 u = *reinterpret_cast<const ushort8*>(p);
  return __builtin_bit_cast(bf16x8, u);
}

DEVI void gload_lds16(const void* g, void* l) {
  __builtin_amdgcn_global_load_lds(
      (const __attribute__((address_space(1))) void*)g,
      (__attribute__((address_space(3))) void*)l, 16, 0, 0);
}

// pack 2 f32 -> u32 of 2 bf16 (RNE)
DEVI int cvtpk(float a, float b) {
  int r;
  asm("v_cvt_pk_bf16_f32 %0, %1, %2" : "=v"(r) : "v"(a), "v"(b));
  return r;
}
// swap a[lanes 32:63] <-> b[lanes 0:31]  (operands MUST hold distinct values --
// equal-valued operands may land in one VGPR, making the swap a no-op; that
// aliasing broke R3's cross-half reduce)
DEVI void pswap(int& a, int& b) {
  asm volatile("v_permlane32_swap_b32 %0, %1" : "+v"(a), "+v"(b));
}
// cross-half combine via shfl (safe codegen)
DEVI float xhalf_sum(float x) { return x + __shfl_xor(x, 32, 64); }

DEVI float tree16sum(const float* p) {
  float a = p[0] + p[1], b = p[2] + p[3], c = p[4] + p[5], d = p[6] + p[7];
  float e = p[8] + p[9], f = p[10] + p[11], g = p[12] + p[13], h = p[14] + p[15];
  a += b; c += d; e += f; g += h;
  return (a + c) + (e + g);
}
// build A/B-fragment (k = hi*8 + i) from 8 P values (keys off..off+7 in C-row order)
DEVI bf16x8 mk_frag(const float* p, int off) {
  int w0 = cvtpk(p[off + 0], p[off + 1]);
  int w1 = cvtpk(p[off + 2], p[off + 3]);
  int w2 = cvtpk(p[off + 4], p[off + 5]);
  int w3 = cvtpk(p[off + 6], p[off + 7]);
  pswap(w0, w2);
  pswap(w1, w3);
  i32x4 v{w0, w1, w2, w3};
  return __builtin_bit_cast(bf16x8, v);
}

// ---------------- fused prep: weight transpose (z<4) + x fp32->bf16 (z>=4) ----
__global__ void prep_kernel(const float* __restrict__ x, unsigned short* __restrict__ xb,
                            const float* __restrict__ Wq, const float* __restrict__ Wk,
                            const float* __restrict__ Wv, const float* __restrict__ Wo,
                            unsigned short* __restrict__ Wtq, unsigned short* __restrict__ Wtk,
                            unsigned short* __restrict__ Wtv, unsigned short* __restrict__ Wto) {
  const int z = blockIdx.z;
  if (z >= 4) {
    // x conversion: 512 blocks x 256 thr x 16 float4 = 8.39M floats
    const int bid = (z - 4) * 256 + blockIdx.y * 16 + blockIdx.x;
    const float4* in4 = reinterpret_cast<const float4*>(x);
    ushort4* out4 = reinterpret_cast<ushort4*>(xb);
#pragma unroll
    for (int j = 0; j < 16; ++j) {
      const int i4 = bid * 4096 + j * 256 + threadIdx.x;
      float4 v = in4[i4];
      ushort4 o;
      o.x = f2bf(v.x); o.y = f2bf(v.y); o.z = f2bf(v.z); o.w = f2bf(v.w);
      out4[i4] = o;
    }
    return;
  }
  __shared__ float tile[64][65];
  const float* W = z == 0 ? Wq : z == 1 ? Wk : z == 2 ? Wv : Wo;
  unsigned short* Wt = z == 0 ? Wtq : z == 1 ? Wtk : z == 2 ? Wtv : Wto;
  const int k0 = blockIdx.x * 64, n0 = blockIdx.y * 64;
  const int tx = threadIdx.x & 63, ty = threadIdx.x >> 6;
  for (int r = ty; r < 64; r += 4)
    tile[r][tx] = W[(size_t)(k0 + r) * D_MODEL + n0 + tx];
  __syncthreads();
  for (int r = ty; r < 64; r += 4)
    Wt[(size_t)(n0 + r) * D_MODEL + k0 + tx] = f2bf(tile[tx][r]);
}

// ---------------- GEMM: C[M=8192][N=1024] = A(bf16) * Wt^T + bias ----------------
// Counted-vmcnt pipeline (T4, proven R11): stage(kt+1) issues 8 vmem/wave;
// s_waitcnt vmcnt(8) waits only the PREVIOUS tile's 8 loads. Raw s_barrier;
// sched_barrier(0) fences per rule 18. Separate launches per R8/R12 lesson:
// QKV fusion is slower regardless of L2 mapping.
__global__ __launch_bounds__(256) void gemm128(
    const unsigned short* __restrict__ A,
    const unsigned short* __restrict__ Bt,
    const float* __restrict__ bias,
    void* __restrict__ outp, int mode, float scale) {
  constexpr int K = 1024, N = 1024, KT = K / 64;
  __shared__ __align__(16) unsigned short As[2][128 * 64];
  __shared__ __align__(16) unsigned short Bs[2][128 * 64];
  const int t = threadIdx.x;
  const int w = t >> 6, l = t & 63;
  // XCD swizzle (bijective: 512 % 8 == 0): A-chunk 2MB + B 2MB = one 4MB L2.
  const int bid2 = ((blockIdx.x & 7) << 6) | (blockIdx.x >> 3);
  const int bm = bid2 >> 3, bn = bid2 & 7;
  const int m0 = bm * 128, n0 = bn * 128;
  const int wm = (w >> 1) * 64, wn = (w & 1) * 64;
  const int lr = l & 15, lg = l >> 4;

  f32x4 acc[4][4] = {};

  auto stage = [&](int kt, int buf) {
    const int k0 = kt * 64;
#pragma unroll
    for (int p = 0; p < 4; ++p) {
      const int seg = p * 4 + w;
      const int row = seg * 8 + (l >> 3);
      const int c = (l & 7) ^ (row & 7);
      gload_lds16(A + (size_t)(m0 + row) * K + k0 + c * 8, &As[buf][seg * 512]);
      gload_lds16(Bt + (size_t)(n0 + row) * K + k0 + c * 8, &Bs[buf][seg * 512]);
    }
  };

  stage(0, 0);
  __syncthreads();   // prologue: full drain once

  for (int kt = 0; kt < KT; ++kt) {
    const int cur = kt & 1;
    if (kt + 1 < KT) {
      stage(kt + 1, cur ^ 1);   // 8 vmem instrs issued per wave
      asm volatile("s_waitcnt vmcnt(8)" ::: "memory");  // prev tile's 8 done
    } else {
      asm volatile("s_waitcnt vmcnt(0)" ::: "memory");  // last tile: drain
    }
    __builtin_amdgcn_sched_barrier(0);
    __builtin_amdgcn_s_barrier();   // all waves see buf[cur] complete
#pragma unroll
    for (int ks = 0; ks < 2; ++ks) {
      bf16x8 af[4], bfr[4];
      const int kk = lg + ks * 4;
#pragma unroll
      for (int i = 0; i < 4; ++i) {
        const int rowA = wm + i * 16 + lr;
        af[i] = ld_bf8(&As[cur][rowA * 64 + ((kk ^ (rowA & 7)) * 8)]);
        const int rowB = wn + i * 16 + lr;
        bfr[i] = ld_bf8(&Bs[cur][rowB * 64 + ((kk ^ (rowB & 7)) * 8)]);
      }
#pragma unroll
      for (int mi = 0; mi < 4; ++mi)
#pragma unroll
        for (int ni = 0; ni < 4; ++ni)
          acc[mi][ni] = __builtin_amdgcn_mfma_f32_16x16x32_bf16(
              af[mi], bfr[ni], acc[mi][ni], 0, 0, 0);
    }
    __builtin_amdgcn_sched_barrier(0);
    __builtin_amdgcn_s_barrier();   // buf[cur] reads done before next stage overwrites
  }

#pragma unroll
  for (int ni = 0; ni < 4; ++ni) {
    const int n = n0 + wn + ni * 16 + lr;
    const float bv = bias[n];
#pragma unroll
    for (int mi = 0; mi < 4; ++mi) {
#pragma unroll
      for (int r = 0; r < 4; ++r) {
        const int m = m0 + wm + mi * 16 + lg * 4 + r;
        const float v = (acc[mi][ni][r] + bv) * scale;
        if (mode == 2) {
          ((float*)outp)[(size_t)m * N + n] = v;
        } else {
          const int b = m >> 11, s = m & 2047, h = n >> 6, dk = n & 63;
          unsigned short* o = (unsigned short*)outp;
          if (mode == 0)
            o[(((size_t)(b * NHEAD + h) * SEQ + s) << 6) + dk] = f2bf(v);
          else
            o[(((size_t)(b * NHEAD + h) << 6) + dk) * SEQ + s] = f2bf(v);
        }
      }
    }
  }
}

// ---------------- causal flash attention v7: counted-vmcnt pipeline ----
// Q: [B*H][S][64] bf16 (pre-scaled by 0.125*log2e); Kt: [B*H][S][64];
// Vt: [B*H][64][S]; Oa: [B][S][1024] bf16.
// R5 math (fixed-shift softmax, swapped QK^T, in-register P). Loop barriers
// use the R11-proven counted-vmcnt pattern: stage issues 4 loads; vmcnt(4)
// waits only the PREVIOUS tile's 4 (a full compute phase old).
__global__ __launch_bounds__(256) void attn_kernel(
    const unsigned short* __restrict__ Q,
    const unsigned short* __restrict__ Kt,
    const unsigned short* __restrict__ Vt,
    unsigned short* __restrict__ Oa) {
  __shared__ __align__(16) unsigned short Ks[2][64 * 64];
  __shared__ __align__(16) unsigned short Vs[2][64 * 64];
  const int t = threadIdx.x, w = t >> 6, l = t & 63;
  const int bid = blockIdx.x;
  // balanced qt permutation: equal column sums so co-resident sets carry equal work
  const int tix = bid >> 6;
  const int tk = tix >> 2, tg = tix & 3;
  const int qt = tk == 0 ? 15 - tg : tk == 1 ? 8 + tg : tk == 2 ? 4 + tg : 3 - tg;
  const int bh = bid & 63;
  const int l31 = l & 31, hi = l >> 5;
  const int jcnt = 2 * qt + 2;
  const int q0w = qt * 128 + w * 32;
  const int qg = q0w + l31;           // this lane's q row

  // Q B-fragments: col=q=l31, k = ks*16 + hi*8 + i  (reused all tiles)
  const unsigned short* Qb = Q + ((size_t)bh * SEQ + qg) * 64;
  bf16x8 qf[4];
#pragma unroll
  for (int ks = 0; ks < 4; ++ks)
    qf[ks] = ld_bf8(Qb + ks * 16 + hi * 8);

  f32x16 psum = {};     // deferred softmax denominator (per C-slot)
  f32x16 oacc[2] = {};  // O^T: col=q=l31, row=d = dt*32+(r&3)+8*(r>>2)+4*hi

  auto stage = [&](int jtile, int buf) {
#pragma unroll
    for (int i = 0; i < 2; ++i) {
      const int seg = w * 2 + i;
      const int row = seg * 8 + (l >> 3);
      const int cg = (l & 7) ^ (row & 7);   // pre-swizzled source chunk
      gload_lds16(Kt + (((size_t)bh * SEQ + jtile * 64 + row) << 6) + cg * 8,
                  &Ks[buf][seg * 512]);
      gload_lds16(Vt + ((size_t)bh * 64 + row) * SEQ + jtile * 64 + cg * 8,
                  &Vs[buf][seg * 512]);
    }
  };

  stage(0, 0);
  __syncthreads();   // prologue: full drain once

  for (int jt = 0; jt < jcnt; ++jt) {
    const int cur = jt & 1;
    if (jt + 1 < jcnt) {
      stage(jt + 1, cur ^ 1);   // 4 vmem instrs issued per wave
      asm volatile("s_waitcnt vmcnt(4)" ::: "memory");  // prev tile's 4 done
    } else {
      asm volatile("s_waitcnt vmcnt(0)" ::: "memory");  // last tile: drain
    }
    __builtin_amdgcn_sched_barrier(0);
    __builtin_amdgcn_s_barrier();   // buf[cur] complete across all waves
    const int j0 = jt * 64;
    const bool active = (j0 <= q0w + 31);   // wave-uniform
    if (active) {
      const bool live1 = (j0 < q0w);        // key subtile 1 has unmasked keys
      const bool maskT = (j0 + 32 >= q0w);  // tile needs causal masking

      // S^T = K * Q^T   (A=K rows=key, B=Q cols=q)
      f32x16 s0 = {}, s1 = {};
      __builtin_amdgcn_s_setprio(1);
#pragma unroll
      for (int ks = 0; ks < 4; ++ks) {
        bf16x8 kf = ld_bf8(&Ks[cur][l31 * 64 + ((((ks << 1) | hi) ^ (l31 & 7)) << 3)]);
        s0 = __builtin_amdgcn_mfma_f32_32x32x16_bf16(kf, qf[ks], s0, 0, 0, 0);
      }
      if (live1) {
#pragma unroll
        for (int ks = 0; ks < 4; ++ks) {
          const int r1 = 32 + l31;
          bf16x8 kf = ld_bf8(&Ks[cur][r1 * 64 + ((((ks << 1) | hi) ^ (r1 & 7)) << 3)]);
          s1 = __builtin_amdgcn_mfma_f32_32x32x16_bf16(kf, qf[ks], s1, 0, 0, 0);
        }
      }
      __builtin_amdgcn_s_setprio(0);

      // P = exp2(S) (masked -> 0), accumulate denominator
      float p0[16];
      if (maskT) {
#pragma unroll
        for (int r = 0; r < 16; ++r) {
          const int key = j0 + (r & 3) + ((r >> 2) << 3) + (hi << 2);
          p0[r] = (key > qg) ? 0.f : exp2f(s0[r]);
        }
      } else {
#pragma unroll
        for (int r = 0; r < 16; ++r) p0[r] = exp2f(s0[r]);
      }
#pragma unroll
      for (int r = 0; r < 16; ++r) psum[r] += p0[r];

      // O^T += V^T * P^T  (A=V^T rows=d from Vs, B=P^T cols=q from regs)
      __builtin_amdgcn_s_setprio(1);
#pragma unroll
      for (int ks = 0; ks < 2; ++ks) {
        bf16x8 pf = mk_frag(p0, ks * 8);
#pragma unroll
        for (int dt = 0; dt < 2; ++dt) {
          const int rv = dt * 32 + l31;
          bf16x8 vf = ld_bf8(&Vs[cur][rv * 64 + ((((ks << 1) | hi) ^ (rv & 7)) << 3)]);
          oacc[dt] = __builtin_amdgcn_mfma_f32_32x32x16_bf16(vf, pf, oacc[dt], 0, 0, 0);
        }
      }
      __builtin_amdgcn_s_setprio(0);

      if (live1) {
        float p1[16];
        if (maskT) {
#pragma unroll
          for (int r = 0; r < 16; ++r) {
            const int key = j0 + 32 + (r & 3) + ((r >> 2) << 3) + (hi << 2);
            p1[r] = (key > qg) ? 0.f : exp2f(s1[r]);
          }
        } else {
#pragma unroll
          for (int r = 0; r < 16; ++r) p1[r] = exp2f(s1[r]);
        }
#pragma unroll
        for (int r = 0; r < 16; ++r) psum[r] += p1[r];
        __builtin_amdgcn_s_setprio(1);
#pragma unroll
        for (int ks = 0; ks < 2; ++ks) {
          bf16x8 pf = mk_frag(p1, ks * 8);
#pragma unroll
          for (int dt = 0; dt < 2; ++dt) {
            const int rv = dt * 32 + l31;
            bf16x8 vf = ld_bf8(&Vs[cur][rv * 64 + (((((ks + 2) << 1) | hi) ^ (rv & 7)) << 3)]);
            oacc[dt] = __builtin_amdgcn_mfma_f32_32x32x16_bf16(vf, pf, oacc[dt], 0, 0, 0);
          }
        }
        __builtin_amdgcn_s_setprio(0);
      }
    }
    __builtin_amdgcn_sched_barrier(0);
    __builtin_amdgcn_s_barrier();   // buf[cur] reads done before next stage overwrites
  }

  // epilogue: reduce denominator once; lane writes its q row
  float pa[16];
#pragma unroll
  for (int r = 0; r < 16; ++r) pa[r] = psum[r];
  const float l_ = xhalf_sum(tree16sum(pa));
  const float rinv = 1.f / l_;
  const int b = bh >> 4, h = bh & 15;
  unsigned short* orow = Oa + ((size_t)(b * SEQ) + qg) * D_MODEL + h * 64;
#pragma unroll
  for (int dt = 0; dt < 2; ++dt)
#pragma unroll
    for (int g = 0; g < 4; ++g) {
      const int d = dt * 32 + g * 8 + hi * 4;
      uint2 u;
      u.x = (unsigned)cvtpk(oacc[dt][g * 4 + 0] * rinv, oacc[dt][g * 4 + 1] * rinv);
      u.y = (unsigned)cvtpk(oacc[dt][g * 4 + 2] * rinv, oacc[dt][g * 4 + 3] * rinv);
      *reinterpret_cast<uint2*>(orow + d) = u;
    }
}

// ---------------- launch ----------------
extern "C" void kernel_launch(void* const* d_in, const int* in_sizes, int n_in,
                              void* d_out, int out_size, void* d_ws, size_t ws_size,
                              hipStream_t stream) {
  const float* x  = (const float*)d_in[0];
  const float* Wq = (const float*)d_in[1];
  const float* bq = (const float*)d_in[2];
  const float* Wk = (const float*)d_in[3];
  const float* bk = (const float*)d_in[4];
  const float* Wv = (const float*)d_in[5];
  const float* bv = (const float*)d_in[6];
  const float* Wo = (const float*)d_in[7];
  const float* bo = (const float*)d_in[8];

  char* ws = (char*)d_ws;
  unsigned short* xb    = (unsigned short*)(ws + 0);
  unsigned short* attnb = (unsigned short*)(ws + 0);  // alias: x dead after V GEMM
  unsigned short* wtq   = (unsigned short*)(ws + 16777216);
  unsigned short* wtk   = (unsigned short*)(ws + 18874368);
  unsigned short* wtv   = (unsigned short*)(ws + 20971520);
  unsigned short* wto   = (unsigned short*)(ws + 23068672);
  unsigned short* Qw    = (unsigned short*)(ws + 25165824);
  unsigned short* Kw    = (unsigned short*)(ws + 41943040);
  unsigned short* Vtw   = (unsigned short*)(ws + 58720256);

  prep_kernel<<<dim3(16, 16, 6), 256, 0, stream>>>(x, xb, Wq, Wk, Wv, Wo,
                                                   wtq, wtk, wtv, wto);

  // Q pre-scaled by 1/sqrt(Dk) * log2(e): attention softmax runs in exp2 domain
  gemm128<<<512, 256, 0, stream>>>(xb, wtq, bq, (void*)Qw, 0, 0.18033688011112042f);
  gemm128<<<512, 256, 0, stream>>>(xb, wtk, bk, (void*)Kw, 0, 1.0f);
  gemm128<<<512, 256, 0, stream>>>(xb, wtv, bv, (void*)Vtw, 1, 1.0f);

  attn_kernel<<<1024, 256, 0, stream>>>(Qw, Kw, Vtw, attnb);

  gemm128<<<512, 256, 0, stream>>>(attnb, wto, bo, d_out, 2, 1.0f);
}